// Round 1
// baseline (1791.641 us; speedup 1.0000x reference)
//
#include <hip/hip_runtime.h>

// Depthwise conv1d, B=8 L=16384 C=512 K=31, SAME padding, fp32.
// out[b,l,c] = sum_k x[b, l+k-15, c] * w[k,c] + bias[c]
//
// Strategy: lanes over channels (contiguous -> coalesced), per-thread register
// sliding window over L. Each thread: 2 channels (float2) x TL=32 outputs.
// Weights held in registers (31 x float2). No LDS. Memory-bound kernel;
// halo rows (30 per 32-output tile) come from L2/L3 via adjacent blocks.

#define BB 8
#define LL 16384
#define CC 512
#define KK 31
#define PAD 15
#define TL 32

__global__ __launch_bounds__(256, 3)
void depthconv1d_2680059592713_kernel(const float* __restrict__ x,
                                      const float* __restrict__ w,
                                      const float* __restrict__ bias,
                                      float* __restrict__ out) {
    const int c2   = threadIdx.x;            // 0..255 -> float2 channel group
    const int tile = blockIdx.x;             // 0 .. B*(L/TL)-1
    const int b    = tile / (LL / TL);
    const int l0   = (tile - b * (LL / TL)) * TL;
    const int c    = c2 * 2;

    // Load per-channel weights into registers: w is (K, C, 1) flat k*C + c.
    float2 wk[KK];
#pragma unroll
    for (int k = 0; k < KK; ++k) {
        wk[k] = *(const float2*)(w + k * CC + c);
    }

    const float2 bv = *(const float2*)(bias + c);

    float2 acc[TL];
#pragma unroll
    for (int t = 0; t < TL; ++t) acc[t] = bv;

    const float* xb = x + ((size_t)b * LL) * CC + c;

    // Stream TL+K-1 input rows; each feeds up to K accumulators.
#pragma unroll
    for (int i = 0; i < TL + KK - 1; ++i) {
        const int li = l0 + i - PAD;         // block-uniform -> uniform branch
        float2 xv;
        if (li >= 0 && li < LL) {
            xv = *(const float2*)(xb + (size_t)li * CC);
        } else {
            xv = make_float2(0.f, 0.f);
        }
#pragma unroll
        for (int t = 0; t < TL; ++t) {
            const int k = i - t;             // compile-time after unroll
            if (k >= 0 && k < KK) {
                acc[t].x = fmaf(xv.x, wk[k].x, acc[t].x);
                acc[t].y = fmaf(xv.y, wk[k].y, acc[t].y);
            }
        }
    }

    float* ob = out + (((size_t)b * LL) + l0) * CC + c;
#pragma unroll
    for (int t = 0; t < TL; ++t) {
        *(float2*)(ob + (size_t)t * CC) = acc[t];
    }
}

extern "C" void kernel_launch(void* const* d_in, const int* in_sizes, int n_in,
                              void* d_out, int out_size, void* d_ws, size_t ws_size,
                              hipStream_t stream) {
    const float* x    = (const float*)d_in[0];
    const float* w    = (const float*)d_in[1];
    const float* bias = (const float*)d_in[2];
    float* out        = (float*)d_out;

    const int n_blocks = BB * (LL / TL);     // 8 * 512 = 4096
    hipLaunchKernelGGL(depthconv1d_2680059592713_kernel,
                       dim3(n_blocks), dim3(256), 0, stream,
                       x, w, bias, out);
}

// Round 2
// 460.693 us; speedup vs baseline: 3.8890x; 3.8890x over previous
//
#include <hip/hip_runtime.h>

// Depthwise conv1d, B=8 L=16384 C=512 K=31, SAME padding, fp32.
// out[b,l,c] = sum_k x[b, l+k-15, c] * w[k,c] + bias[c]
//
// R1 post-mortem: TL=32 + launch_bounds(256,3) -> compiler kept acc[]/wk[] in
// scratch (VGPR_Count=40, FETCH 4 GB of scratch traffic, 1518 us). Fix: TL=16
// so the fully-unrolled triangle is ~500 FMAs and total register demand ~115
// VGPRs, and no waves/EU floor so the allocator can actually use registers.
// Lanes over channels (float2 -> coalesced dwordx2), per-thread register
// sliding window over L, weights in registers, no LDS. Halo rows (30 per
// 16-output tile) are served by L2/L3 (whole input fits in the 256 MB L3).

#define BB 8
#define LL 16384
#define CC 512
#define KK 31
#define PAD 15
#define TL 16
#define TILES_PER_B (LL / TL)   // 1024

__global__ __launch_bounds__(256)
void depthconv1d_2680059592713_kernel(const float* __restrict__ x,
                                      const float* __restrict__ w,
                                      const float* __restrict__ bias,
                                      float* __restrict__ out) {
    const int c2   = threadIdx.x;                 // 0..255 -> float2 channel group
    const int tile = blockIdx.x;                  // 0 .. B*TILES_PER_B-1
    const int b    = tile >> 10;                  // / 1024
    const int l0   = (tile & (TILES_PER_B - 1)) * TL;
    const int c    = c2 * 2;

    // Weights: w is (K, C, 1) flat k*C + c. 31 x float2 = 62 VGPRs.
    float2 wk[KK];
#pragma unroll
    for (int k = 0; k < KK; ++k) {
        wk[k] = *(const float2*)(w + k * CC + c);
    }

    const float2 bv = *(const float2*)(bias + c);

    float2 acc[TL];
#pragma unroll
    for (int t = 0; t < TL; ++t) acc[t] = bv;

    const float* xb = x + ((size_t)b * LL) * CC + c;

    // Stream TL+K-1 = 46 input rows; row i feeds acc[t] with tap k = i-t.
#pragma unroll
    for (int i = 0; i < TL + KK - 1; ++i) {
        const int li = l0 + i - PAD;              // block-uniform -> uniform branch
        float2 xv;
        if (li >= 0 && li < LL) {
            xv = *(const float2*)(xb + (size_t)li * CC);
        } else {
            xv = make_float2(0.f, 0.f);
        }
#pragma unroll
        for (int t = 0; t < TL; ++t) {
            const int k = i - t;                  // constant after full unroll
            if (k >= 0 && k < KK) {
                acc[t].x = fmaf(xv.x, wk[k].x, acc[t].x);
                acc[t].y = fmaf(xv.y, wk[k].y, acc[t].y);
            }
        }
    }

    float* ob = out + (((size_t)b * LL) + l0) * CC + c;
#pragma unroll
    for (int t = 0; t < TL; ++t) {
        *(float2*)(ob + (size_t)t * CC) = acc[t];
    }
}

extern "C" void kernel_launch(void* const* d_in, const int* in_sizes, int n_in,
                              void* d_out, int out_size, void* d_ws, size_t ws_size,
                              hipStream_t stream) {
    const float* x    = (const float*)d_in[0];
    const float* w    = (const float*)d_in[1];
    const float* bias = (const float*)d_in[2];
    float* out        = (float*)d_out;

    const int n_blocks = BB * TILES_PER_B;        // 8 * 1024 = 8192
    hipLaunchKernelGGL(depthconv1d_2680059592713_kernel,
                       dim3(n_blocks), dim3(256), 0, stream,
                       x, w, bias, out);
}